// Round 3
// baseline (426.447 us; speedup 1.0000x reference)
//
#include <hip/hip_runtime.h>
#include <math.h>

// ---------------------------------------------------------------------------
// NTM cell. ALL I/O fp32; bf16 MFMA internally for the LSTM GEMM.
// B=4096, IN=64, U=256, N=128, W=64, OUT=64, NPH=70, P=268, K_lstm=384.
// Pipeline: k_transpose -> k_lstm (MFMA) -> k_params -> k_addr -> k_out
// k_addr: wave-per-row, barrier-light, no M staging in LDS (direct global,
// re-read hits L2/L3). Round-2 version was latency-bound (35% VALU, 29% HBM,
// 38KB LDS -> 4 blocks/CU, 7 barriers).
// ---------------------------------------------------------------------------

typedef unsigned short u16;
typedef __attribute__((ext_vector_type(8))) __bf16 bf16x8;
typedef __attribute__((ext_vector_type(8))) unsigned short u16x8;
typedef __attribute__((ext_vector_type(4))) float f32x4;

#define DI __device__ __forceinline__

static constexpr int Bn = 4096;

// output element offsets (order: out, read_vec, w_read, w_write, M_new, h_new, c_new)
static constexpr size_t OFF_OUT = 0;
static constexpr size_t OFF_RV  = (size_t)Bn * 64;
static constexpr size_t OFF_WR  = OFF_RV + (size_t)Bn * 64;
static constexpr size_t OFF_WW  = OFF_WR + (size_t)Bn * 128;
static constexpr size_t OFF_M   = OFF_WW + (size_t)Bn * 128;
static constexpr size_t OFF_H   = OFF_M + (size_t)Bn * 128 * 64;
static constexpr size_t OFF_C   = OFF_H + (size_t)Bn * 256;

// ws byte offsets
static constexpr size_t WS_WT = 0;                             // bf16 1024x384
static constexpr size_t WS_H  = 786432;                        // f32 4096x256
static constexpr size_t WS_P  = WS_H + (size_t)Bn * 256 * 4;   // f32 4096x268
static constexpr size_t WS_RV = WS_P + (size_t)Bn * 268 * 4;   // f32 4096x64

DI u16 f2b(float f) {
  unsigned int u = __float_as_uint(f);
  unsigned int r = (u + 0x7fffu + ((u >> 16) & 1u)) >> 16;  // RNE
  return (u16)r;
}
DI float sigf(float x) { return 1.f / (1.f + expf(-x)); }

DI void gld16(const void* g, void* l) {
  __builtin_amdgcn_global_load_lds(
      (const __attribute__((address_space(1))) unsigned int*)g,
      (__attribute__((address_space(3))) unsigned int*)l, 16, 0, 0);
}

DI float wsum(float v) {
  v += __shfl_xor(v, 32, 64); v += __shfl_xor(v, 16, 64);
  v += __shfl_xor(v, 8, 64);  v += __shfl_xor(v, 4, 64);
  v += __shfl_xor(v, 2, 64);  v += __shfl_xor(v, 1, 64);
  return v;
}
DI float wmax(float v) {
  v = fmaxf(v, __shfl_xor(v, 32, 64)); v = fmaxf(v, __shfl_xor(v, 16, 64));
  v = fmaxf(v, __shfl_xor(v, 8, 64));  v = fmaxf(v, __shfl_xor(v, 4, 64));
  v = fmaxf(v, __shfl_xor(v, 2, 64));  v = fmaxf(v, __shfl_xor(v, 1, 64));
  return v;
}

// ---------------------------------------------------------------------------
// K0: Wt[c][k] = bf16( k<128 ? W_k[k][c] : W_r[k-128][c] )   c<1024, k<384
// ---------------------------------------------------------------------------
__global__ __launch_bounds__(256) void k_transpose(
    const float* __restrict__ W_k, const float* __restrict__ W_r, u16* __restrict__ Wt)
{
  __shared__ float tile[64][65];
  const int c0 = blockIdx.x * 64, k0 = blockIdx.y * 64;
  const int t = threadIdx.x;
  {
    const int r2 = t >> 4, cc = (t & 15) * 4;
#pragma unroll
    for (int rr = 0; rr < 4; rr++) {
      int row = rr * 16 + r2;  // k-row within block
      const float* src = (k0 < 128) ? (W_k + (size_t)(k0 + row) * 1024)
                                    : (W_r + (size_t)(k0 - 128 + row) * 1024);
      float4 v = *(const float4*)(src + c0 + cc);
      tile[row][cc + 0] = v.x; tile[row][cc + 1] = v.y;
      tile[row][cc + 2] = v.z; tile[row][cc + 3] = v.w;
    }
  }
  __syncthreads();
  const int wr = t >> 2, wc0 = (t & 3) * 16;
  u16* dst = Wt + (size_t)(c0 + wr) * 384 + k0 + wc0;
#pragma unroll
  for (int j = 0; j < 16; j++) dst[j] = f2b(tile[wc0 + j][wr]);
}

// ---------------------------------------------------------------------------
// K1: fused LSTM. z = [x|rv0|h0] @ [W_k;W_r] + b -> gates -> h_new, c_new.
// ---------------------------------------------------------------------------
__global__ __launch_bounds__(256) void k_lstm(
    const float* __restrict__ x, const float* __restrict__ rv0, const float* __restrict__ h0,
    const float* __restrict__ c0, const float* __restrict__ b_lstm, const u16* __restrict__ Wt,
    float* __restrict__ h_ws, float* __restrict__ out)
{
  __shared__ __align__(16) u16 As[64 * 32];   // 4 KB
  __shared__ __align__(16) u16 Bs[128 * 32];  // 8 KB
  const int t = threadIdx.x;
  const int wv = t >> 6, lane = t & 63;
  const int m0 = blockIdx.x * 64, u0 = blockIdx.y * 32;
  const int lane15 = lane & 15, quad = lane >> 4;

  f32x4 acc[8];
#pragma unroll
  for (int i = 0; i < 8; i++) acc[i] = (f32x4){0.f, 0.f, 0.f, 0.f};

  const int mrow = wv * 16 + lane15;
  const int aChunk = mrow * 4 + (quad ^ (mrow & 3));

  for (int kstep = 0; kstep < 12; ++kstep) {
    const int k0 = kstep * 32;
    const float* srcA; int ldA, colA;
    if (k0 < 64)       { srcA = x;   ldA = 64;  colA = k0; }
    else if (k0 < 128) { srcA = rv0; ldA = 64;  colA = k0 - 64; }
    else               { srcA = h0;  ldA = 256; colA = k0 - 128; }
    {
      const int m = t >> 2, kq = t & 3;
      const float* ap = srcA + (size_t)(m0 + m) * ldA + colA + kq * 8;
      float4 v0 = *(const float4*)ap;
      float4 v1 = *(const float4*)(ap + 4);
      u16x8 pk;
      pk[0] = f2b(v0.x); pk[1] = f2b(v0.y); pk[2] = f2b(v0.z); pk[3] = f2b(v0.w);
      pk[4] = f2b(v1.x); pk[5] = f2b(v1.y); pk[6] = f2b(v1.z); pk[7] = f2b(v1.w);
      *(u16x8*)(As + (m * 4 + (kq ^ (m & 3))) * 8) = pk;
    }
#pragma unroll
    for (int r = 0; r < 2; ++r) {
      int lin = r * 256 + t;
      int cl = lin >> 2, kq = (lin & 3) ^ (cl & 3);
      int cg = (cl >> 5) * 256 + u0 + (cl & 31);  // gate-stripe gather
      gld16(Wt + (size_t)cg * 384 + k0 + kq * 8, Bs + lin * 8);
    }
    __syncthreads();
    bf16x8 a = *(const bf16x8*)(As + aChunk * 8);
#pragma unroll
    for (int nt = 0; nt < 8; ++nt) {
      int crow = nt * 16 + lane15;
      bf16x8 bfr = *(const bf16x8*)(Bs + (crow * 4 + (quad ^ (crow & 3))) * 8);
      acc[nt] = __builtin_amdgcn_mfma_f32_16x16x32_bf16(a, bfr, acc[nt], 0, 0, 0);
    }
    __syncthreads();
  }

#pragma unroll
  for (int up = 0; up < 2; ++up) {
    const int u = u0 + up * 16 + lane15;
    const float bi  = b_lstm[u];
    const float bff = b_lstm[256 + u];
    const float bg  = b_lstm[512 + u];
    const float bo  = b_lstm[768 + u];
#pragma unroll
    for (int r = 0; r < 4; ++r) {
      const int brow = m0 + wv * 16 + quad * 4 + r;
      float zi = acc[0 + up][r] + bi;
      float zf = acc[2 + up][r] + bff;
      float zg = acc[4 + up][r] + bg;
      float zo = acc[6 + up][r] + bo;
      float cold = c0[(size_t)brow * 256 + u];
      float cn = sigf(zf) * cold + sigf(zi) * tanhf(zg);
      float hn = sigf(zo) * tanhf(cn);
      h_ws[(size_t)brow * 256 + u] = hn;
      out[OFF_H + (size_t)brow * 256 + u] = hn;
      out[OFF_C + (size_t)brow * 256 + u] = cn;
    }
  }
}

// ---------------------------------------------------------------------------
// K2: params = clip(h_new @ W_p + b_p, +-20). 8 rows/block, 512 blocks.
// ---------------------------------------------------------------------------
__global__ __launch_bounds__(320) void k_params(
    const float* __restrict__ h_ws, const float* __restrict__ W_p,
    const float* __restrict__ b_p, float* __restrict__ p_ws)
{
  __shared__ float hs[8][256];  // 8 KB
  const int b0 = blockIdx.x * 8, t = threadIdx.x;
#pragma unroll
  for (int i = 0; i < 7; i++) {
    int lin = i * 320 + t;
    if (lin < 2048) hs[lin >> 8][lin & 255] = h_ws[(size_t)b0 * 256 + lin];
  }
  __syncthreads();
  if (t < 268) {
    float acc[8];
#pragma unroll
    for (int r = 0; r < 8; r++) acc[r] = 0.f;
    for (int k4 = 0; k4 < 64; k4++) {
      float wp0 = W_p[(k4 * 4 + 0) * 268 + t];
      float wp1 = W_p[(k4 * 4 + 1) * 268 + t];
      float wp2 = W_p[(k4 * 4 + 2) * 268 + t];
      float wp3 = W_p[(k4 * 4 + 3) * 268 + t];
#pragma unroll
      for (int r = 0; r < 8; r++) {
        f32x4 h4 = *(const f32x4*)&hs[r][k4 * 4];
        acc[r] += h4[0] * wp0 + h4[1] * wp1 + h4[2] * wp2 + h4[3] * wp3;
      }
    }
    float bp = b_p[t];
#pragma unroll
    for (int r = 0; r < 8; r++) {
      float v = fminf(fmaxf(acc[r] + bp, -20.f), 20.f);
      p_ws[(size_t)(b0 + r) * 268 + t] = v;
    }
  }
}

// ---------------------------------------------------------------------------
// K3: addressing + read_vec + M_new. Wave-per-row (4 rows/block, grid B/4).
// No M in LDS; all cross-lane via shuffles + tiny LDS broadcast tables.
// ---------------------------------------------------------------------------
__global__ __launch_bounds__(256, 4) void k_addr(
    const float* __restrict__ M, const float* __restrict__ w0p, const float* __restrict__ w1p,
    const float* __restrict__ params, float* __restrict__ rv_ws, float* __restrict__ out)
{
  __shared__ float knL[4][2][64];   // normalized keys, per wave
  __shared__ float wfL[4][2][128];  // final weights, per wave

  const int t = threadIdx.x, wv = t >> 6, ln = t & 63;
  const int b = blockIdx.x * 4 + wv;
  const float* p = params + (size_t)b * 268;

  // Phase 1: normalized keys (lane = w)
  float kv0 = tanhf(p[ln]);
  float kv1 = tanhf(p[70 + ln]);
  float ss0 = wsum(kv0 * kv0);
  float ss1 = wsum(kv1 * kv1);
  knL[wv][0][ln] = kv0 * rsqrtf(fmaxf(ss0, 1e-12f));
  knL[wv][1][ln] = kv1 * rsqrtf(fmaxf(ss1, 1e-12f));
  __syncthreads();

  // Phase 2: lane ln owns rows nA=2ln, nB=2ln+1; full-row dots in-lane.
  // kn reads are wave-uniform LDS addresses -> broadcast (conflict-free).
  const float* mr = M + (size_t)b * 8192 + ln * 128;
  float ssA = 0.f, drA = 0.f, dwA = 0.f, ssB = 0.f, drB = 0.f, dwB = 0.f;
#pragma unroll
  for (int q = 0; q < 16; q++) {
    f32x4 a  = *(const f32x4*)(mr + q * 4);
    f32x4 bb = *(const f32x4*)(mr + 64 + q * 4);
    f32x4 k0 = *(const f32x4*)&knL[wv][0][q * 4];
    f32x4 k1 = *(const f32x4*)&knL[wv][1][q * 4];
#pragma unroll
    for (int j = 0; j < 4; j++) {
      ssA += a[j] * a[j];  drA += k0[j] * a[j];  dwA += k1[j] * a[j];
      ssB += bb[j] * bb[j]; drB += k0[j] * bb[j]; dwB += k1[j] * bb[j];
    }
  }
  float invA = rsqrtf(fmaxf(ssA, 1e-12f));
  float invB = rsqrtf(fmaxf(ssB, 1e-12f));
  float ksA[2] = { -drA * invA, -dwA * invA };  // negative cosine sim (faithful)
  float ksB[2] = { -drB * invB, -dwB * invB };

  // Phase 3: softmax -> interpolate -> shift -> sharpen, per head, in-wave.
#pragma unroll
  for (int h = 0; h < 2; h++) {
    const float* ph = p + h * 70;
    float beta = log1pf(expf(ph[64]));
    float g = sigf(ph[65]);
    float a0 = ph[66], a1 = ph[67], a2 = ph[68];
    float mx3 = fmaxf(a0, fmaxf(a1, a2));
    float e0 = expf(a0 - mx3), e1 = expf(a1 - mx3), e2 = expf(a2 - mx3);
    float is3 = 1.f / (e0 + e1 + e2);
    float sh0 = e0 * is3, sh1 = e1 * is3, sh2 = e2 * is3;
    float gam = log1pf(expf(ph[69])) + 1.f;

    float vA = beta * ksA[h], vB = beta * ksB[h];
    float mxw = wmax(fmaxf(vA, vB));
    float eA = expf(vA - mxw), eB = expf(vB - mxw);
    float s = wsum(eA + eB);
    float wcA = eA / s, wcB = eB / s;
    const float* wpp = h ? w1p : w0p;
    float2 wp = *(const float2*)(wpp + (size_t)b * 128 + 2 * ln);
    float wgA = g * wcA + (1.f - g) * wp.x;
    float wgB = g * wcB + (1.f - g) * wp.y;
    // shift: w_[n] = sh0*wg[n] + sh1*wg[n-1] + sh2*wg[n+1] (circular)
    float left  = __shfl(wgB, (ln + 63) & 63);  // wg[2ln-1]
    float right = __shfl(wgA, (ln + 1) & 63);   // wg[2ln+2]
    float w_A = sh0 * wgA + sh1 * left + sh2 * wgB;
    float w_B = sh0 * wgB + sh1 * wgA + sh2 * right;
    float pA = powf(w_A, gam), pB = powf(w_B, gam);
    float sp = wsum(pA + pB);
    float wfA = pA / sp, wfB = pB / sp;
    wfL[wv][h][2 * ln] = wfA;
    wfL[wv][h][2 * ln + 1] = wfB;
    *(float2*)(out + (h ? OFF_WW : OFF_WR) + (size_t)b * 128 + 2 * ln) =
        make_float2(wfA, wfB);
  }
  __syncthreads();

  // Phase 4: read_vec + M_new, column-parallel (lane = w), coalesced.
  {
    float er = sigf(p[140 + ln]);
    float ad = tanhf(p[204 + ln]);
    const float* mc = M + (size_t)b * 8192;
    float* mo = out + OFF_M + (size_t)b * 8192;
    float rv = 0.f;
#pragma unroll 4
    for (int np = 0; np < 64; np++) {
      float2 wrp = *(const float2*)&wfL[wv][0][2 * np];  // broadcast
      float2 wwp = *(const float2*)&wfL[wv][1][2 * np];
      float mA = mc[(2 * np) * 64 + ln];
      float mB = mc[(2 * np + 1) * 64 + ln];
      rv += wrp.x * mA + wrp.y * mB;
      mo[(2 * np) * 64 + ln]     = mA * (1.f - wwp.x * er) + wwp.x * ad;
      mo[(2 * np + 1) * 64 + ln] = mB * (1.f - wwp.y * er) + wwp.y * ad;
    }
    out[OFF_RV + (size_t)b * 64 + ln] = rv;
    rv_ws[(size_t)b * 64 + ln] = rv;
  }
}

// ---------------------------------------------------------------------------
// K4: out = clip([h_new, read_vec] @ W_o + b_o, +-20). 8 rows/block, 512 blocks.
// ---------------------------------------------------------------------------
__global__ __launch_bounds__(256) void k_out(
    const float* __restrict__ h_ws, const float* __restrict__ rv_ws,
    const float* __restrict__ W_o, const float* __restrict__ b_o, float* __restrict__ out)
{
  __shared__ float in_s[8][320];  // 10 KB
  const int b0 = blockIdx.x * 8, t = threadIdx.x;
#pragma unroll
  for (int i = 0; i < 8; i++) {
    int lin = i * 256 + t;
    in_s[lin >> 8][lin & 255] = h_ws[(size_t)b0 * 256 + lin];
  }
#pragma unroll
  for (int i = 0; i < 2; i++) {
    int lin = i * 256 + t;
    in_s[lin >> 6][256 + (lin & 63)] = rv_ws[(size_t)b0 * 64 + lin];
  }
  __syncthreads();
  const int c = t & 63, rg = t >> 6;  // 4 wave-groups x 2 rows
  float a0 = 0.f, a1 = 0.f;
#pragma unroll 4
  for (int k = 0; k < 320; k++) {
    float wo = W_o[k * 64 + c];
    a0 += in_s[rg * 2][k] * wo;
    a1 += in_s[rg * 2 + 1][k] * wo;
  }
  float bo = b_o[c];
  out[OFF_OUT + (size_t)(b0 + rg * 2) * 64 + c]     = fminf(fmaxf(a0 + bo, -20.f), 20.f);
  out[OFF_OUT + (size_t)(b0 + rg * 2 + 1) * 64 + c] = fminf(fmaxf(a1 + bo, -20.f), 20.f);
}

// ---------------------------------------------------------------------------
extern "C" void kernel_launch(void* const* d_in, const int* in_sizes, int n_in,
                              void* d_out, int out_size, void* d_ws, size_t ws_size,
                              hipStream_t stream)
{
  const float* x   = (const float*)d_in[0];
  const float* h0  = (const float*)d_in[1];
  const float* c0  = (const float*)d_in[2];
  const float* rv0 = (const float*)d_in[3];
  const float* w0p = (const float*)d_in[4];
  const float* w1p = (const float*)d_in[5];
  const float* M   = (const float*)d_in[6];
  const float* W_k = (const float*)d_in[7];
  const float* W_r = (const float*)d_in[8];
  const float* b_l = (const float*)d_in[9];
  const float* W_p = (const float*)d_in[10];
  const float* b_p = (const float*)d_in[11];
  const float* W_o = (const float*)d_in[12];
  const float* b_o = (const float*)d_in[13];
  float* out = (float*)d_out;
  char* ws = (char*)d_ws;
  u16*   Wt    = (u16*)(ws + WS_WT);
  float* h_ws  = (float*)(ws + WS_H);
  float* p_ws  = (float*)(ws + WS_P);
  float* rv_ws = (float*)(ws + WS_RV);

  k_transpose<<<dim3(16, 6), 256, 0, stream>>>(W_k, W_r, Wt);
  k_lstm<<<dim3(64, 8), 256, 0, stream>>>(x, rv0, h0, c0, b_l, Wt, h_ws, out);
  k_params<<<512, 320, 0, stream>>>(h_ws, W_p, b_p, p_ws);
  k_addr<<<1024, 256, 0, stream>>>(M, w0p, w1p, p_ws, rv_ws, out);
  k_out<<<512, 256, 0, stream>>>(h_ws, rv_ws, W_o, b_o, out);
}